// Round 4
// baseline (532.025 us; speedup 1.0000x reference)
//
#include <hip/hip_runtime.h>

#define EPS 1e-6f

using bfrag = __attribute__((ext_vector_type(8))) short;   // 8 bf16
using ffrag = __attribute__((ext_vector_type(4))) float;   // C/D frag
typedef unsigned short ushortT;

#define MFMA(a, b, c) __builtin_amdgcn_mfma_f32_16x16x32_bf16((a), (b), (c), 0, 0, 0)

__device__ __forceinline__ ushortT bf_hi(float x) {
  unsigned u = __builtin_bit_cast(unsigned, x);
  return (ushortT)((u + 0x7FFFu + ((u >> 16) & 1u)) >> 16);
}
__device__ __forceinline__ float bf_f(ushortT h) {
  unsigned u = (unsigned)h << 16;
  return __builtin_bit_cast(float, u);
}
__device__ __forceinline__ void split_bf(float f, short& h, short& l) {
  ushortT hi = bf_hi(f);
  h = (short)hi;
  l = (short)bf_hi(f - bf_f(hi));
}
__device__ __forceinline__ int op_of(int k) { return (k < 4) ? k : ((k >> 1) + 2); }

// ---------------------------------------------------------------------------
// ws layout (bytes): Gp 0..256K | W1p 256K..384K | W2p 384K..448K | cbias 448K+
// Weights are bf16 (hi-only). Packed B-fragment order for W[K x N]:
//   elem j of lane L = W[kk*32 + (L>>4)*8 + j][nt*16 + (L&15)]
//   flat ((ntIdx*ksteps + kk)*64 + L)*8 + j
// ---------------------------------------------------------------------------
__global__ void prologue(const float* __restrict__ ops_W1,
                         const float* __restrict__ ops_W2,
                         const float* __restrict__ ops_b2,
                         const float* __restrict__ pres_W1,
                         const float* __restrict__ pres_b1,
                         const float* __restrict__ pres_W2,
                         const float* __restrict__ pres_b2,
                         const float* __restrict__ fus_W1,
                         const float* __restrict__ fus_b1,
                         const float* __restrict__ fus_W2,
                         ushortT* __restrict__ Gp,
                         ushortT* __restrict__ W1p,
                         ushortT* __restrict__ W2p,
                         float* __restrict__ cb) {
  const int blk = blockIdx.x;
  const int tid = threadIdx.x;

  if (blk < 512) {
    // ---- pack G: G[r][n] = sum_d ops_W2[op(k)][h][d] * fus_W1[k*128+d][n]
    int r = blk, n = tid;
    int k = r >> 6, h = r & 63;
    int op = op_of(k);
    const float* w2 = ops_W2 + (size_t)(op * 64 + h) * 128;
    const float* w1 = fus_W1 + (size_t)(k * 128) * 256 + n;
    float a0 = 0.f, a1 = 0.f, a2 = 0.f, a3 = 0.f;
#pragma unroll 8
    for (int d = 0; d < 128; d += 4) {
      a0 = fmaf(w2[d], w1[(size_t)d * 256], a0);
      a1 = fmaf(w2[d + 1], w1[(size_t)(d + 1) * 256], a1);
      a2 = fmaf(w2[d + 2], w1[(size_t)(d + 2) * 256], a2);
      a3 = fmaf(w2[d + 3], w1[(size_t)(d + 3) * 256], a3);
    }
    float acc = (a0 + a1) + (a2 + a3);
    int nt = n >> 4, kk = r >> 5, quad = (r >> 3) & 3, j = r & 7;
    int lane = quad * 16 + (n & 15);
    Gp[((nt * 16 + kk) * 64 + lane) * 8 + j] = bf_hi(acc);
  } else if (blk < 544) {
    // ---- pack ops_W1: [k 8][nt 4][kk 4][lane 64][j 8]
    int gid = (blk - 512) * 256 + tid;   // 0..8191
    int lane = gid & 63, kk = (gid >> 6) & 3, nt = (gid >> 8) & 3, k = gid >> 10;
    int op = op_of(k);
    int col = nt * 16 + (lane & 15);
#pragma unroll
    for (int j = 0; j < 8; ++j) {
      int d = kk * 32 + ((lane >> 4) & 3) * 8 + j;
      W1p[gid * 8 + j] = bf_hi(ops_W1[((size_t)op * 128 + d) * 64 + col]);
    }
  } else if (blk < 560) {
    // ---- pack fus_W2: [nt 8][kk 8][lane 64][j 8]
    int gid = (blk - 544) * 256 + tid;   // 0..4095
    int lane = gid & 63, kk = (gid >> 6) & 7, nt = gid >> 9;
    int col = nt * 16 + (lane & 15);
#pragma unroll
    for (int j = 0; j < 8; ++j) {
      int d = kk * 32 + ((lane >> 4) & 3) * 8 + j;
      W2p[gid * 8 + j] = bf_hi(fus_W2[(size_t)d * 128 + col]);
    }
  } else {
    // ---- cbias[c][n]
    int c = blk - 560, n = tid;
    __shared__ float hrelu[64];
    __shared__ float ptok[128];
    if (n < 64) hrelu[n] = fmaxf(pres_W1[c * 64 + n] + pres_b1[n], 0.f);
    __syncthreads();
    if (n < 128) {
      float p0 = pres_b2[n], p1 = 0.f;
#pragma unroll 8
      for (int hh = 0; hh < 64; hh += 2) {
        p0 = fmaf(hrelu[hh], pres_W2[hh * 128 + n], p0);
        p1 = fmaf(hrelu[hh + 1], pres_W2[(hh + 1) * 128 + n], p1);
      }
      ptok[n] = p0 + p1;
    }
    __syncthreads();
    float acc = fus_b1[n];
#pragma unroll 4
    for (int d = 0; d < 128; ++d)
      acc = fmaf(ptok[d], fus_W1[(size_t)(1024 + d) * 256 + n], acc);
    float acc2 = 0.f;  // ops_b2 fold (zeros in setup, kept for generality)
    for (int k = 0; k < 8; ++k) {
      int op = op_of(k);
#pragma unroll 4
      for (int d = 0; d < 128; ++d)
        acc2 = fmaf(ops_b2[op * 128 + d], fus_W1[(size_t)(k * 128 + d) * 256 + n], acc2);
    }
    cb[c * 256 + n] = acc + acc2;
  }
}

// ---------------------------------------------------------------------------
// Main: 32 tokens/block (two 16-row M-tiles), 256 threads = 4 waves.
// Phase 2 builds MFMA A-fragments DIRECTLY from x in registers (lane L serves
// token c0=L&15 at dims quad*8+j + kk*32) -> no F LDS, no per-op barriers.
// Weights bf16 (hi only); activations split hi+lo (2 MFMAs per product).
// Split-K: H[32][256] hi/lo built & consumed in two rounds (ops 0-3, 4-7).
// Hid (phase-4 input) bf16-hi only, aliases H. LDS 33.9 KB -> 3 blocks/CU.
// k=5 feature = -(k=4) with same op-4 MLP -> derived from k=4 accumulator.
// ---------------------------------------------------------------------------
template <int K, int KB, bool NEG5>
__device__ __forceinline__ void p2op(int tile, int wv, int lane, int quad, int c0,
                                     const float (&af)[32], const float (&bf)[32],
                                     float invA, float invB,
                                     ushortT (*Hh)[264], ushortT (*Hl)[264],
                                     const ushortT* __restrict__ W1p,
                                     const float* __restrict__ ops_b1) {
  bfrag ah[4], al[4];
#pragma unroll
  for (int kk = 0; kk < 4; ++kk) {
#pragma unroll
    for (int j = 0; j < 8; ++j) {
      float a = af[kk * 8 + j], b = bf[kk * 8 + j], f;
      if constexpr (K == 0)      f = a * b;
      else if constexpr (K == 1) f = a + b;
      else if constexpr (K == 2) f = (a * invA) * (b * invB);
      else if constexpr (K == 3) f = fabsf(a - b);
      else if constexpr (K == 4) f = a - b;
      else if constexpr (K == 6) f = a * __builtin_amdgcn_rcpf(b + EPS);
      else                       f = b * __builtin_amdgcn_rcpf(a + EPS);
      short h, l;
      split_bf(f, h, l);
      ah[kk][j] = h;
      al[kk][j] = l;
    }
  }
  constexpr int OP = (K < 4) ? K : ((K >> 1) + 2);
  const ushortT* wp = W1p + ((K * 4 + wv) * 4) * 512 + lane * 8;
  ffrag s = {0.f, 0.f, 0.f, 0.f};
#pragma unroll
  for (int kk = 0; kk < 4; ++kk) {
    bfrag bh = *(const bfrag*)(wp + kk * 512);
    s = MFMA(ah[kk], bh, s);
    s = MFMA(al[kk], bh, s);
  }
  const float bb1 = ops_b1[OP * 64 + wv * 16 + c0];
  const int col = KB * 64 + wv * 16 + c0;
  const int rbase = tile * 16 + quad * 4;
#pragma unroll
  for (int i = 0; i < 4; ++i) {
    short h, l;
    split_bf(fmaxf(s[i] + bb1, 0.f), h, l);
    Hh[rbase + i][col] = (ushortT)h;
    Hl[rbase + i][col] = (ushortT)l;
    if constexpr (NEG5) {   // k=5 feature = -f4, same op-4 W1/b1
      split_bf(fmaxf(-s[i] + bb1, 0.f), h, l);
      Hh[rbase + i][col + 64] = (ushortT)h;
      Hl[rbase + i][col + 64] = (ushortT)l;
    }
  }
}

__device__ __forceinline__ void ldrow(const float* p, float (&r)[32]) {
#pragma unroll
  for (int kk = 0; kk < 4; ++kk) {
    float4 t0 = *(const float4*)(p + kk * 32);
    float4 t1 = *(const float4*)(p + kk * 32 + 4);
    r[kk * 8 + 0] = t0.x; r[kk * 8 + 1] = t0.y; r[kk * 8 + 2] = t0.z; r[kk * 8 + 3] = t0.w;
    r[kk * 8 + 4] = t1.x; r[kk * 8 + 5] = t1.y; r[kk * 8 + 6] = t1.z; r[kk * 8 + 7] = t1.w;
  }
}

__device__ __forceinline__ void p3round(int r, int wv, int lane, int quad, int c0,
                                        ushortT (*Hh)[264], ushortT (*Hl)[264],
                                        const ushortT* __restrict__ Gp,
                                        ffrag (&u)[4], ffrag (&v)[4]) {
#pragma unroll
  for (int kk = 0; kk < 8; ++kk) {
    bfrag ah0 = *(const bfrag*)&Hh[c0][kk * 32 + quad * 8];
    bfrag al0 = *(const bfrag*)&Hl[c0][kk * 32 + quad * 8];
    bfrag ah1 = *(const bfrag*)&Hh[16 + c0][kk * 32 + quad * 8];
    bfrag al1 = *(const bfrag*)&Hl[16 + c0][kk * 32 + quad * 8];
#pragma unroll
    for (int nt4 = 0; nt4 < 4; ++nt4) {
      bfrag g = *(const bfrag*)(Gp + (((wv * 4 + nt4) * 16 + r * 8 + kk) * 64 + lane) * 8);
      u[nt4] = MFMA(ah0, g, u[nt4]);
      u[nt4] = MFMA(al0, g, u[nt4]);
      v[nt4] = MFMA(ah1, g, v[nt4]);
      v[nt4] = MFMA(al1, g, v[nt4]);
    }
  }
}

__global__ __launch_bounds__(256, 3)
void drel_main(const float* __restrict__ x, const int* __restrict__ presence,
               const int* __restrict__ idx_i, const int* __restrict__ idx_j,
               const float* __restrict__ ops_b1, const float* __restrict__ fus_b2,
               const ushortT* __restrict__ W1p, const ushortT* __restrict__ Gp,
               const ushortT* __restrict__ W2p, const float* __restrict__ cbias,
               float* __restrict__ out) {
  __shared__ __align__(16) char smem[33920];
  ushortT (*Hh)[264] = reinterpret_cast<ushortT(*)[264]>(smem);
  ushortT (*Hl)[264] = reinterpret_cast<ushortT(*)[264]>(smem + 16896);
  ushortT (*Dh)[264] = reinterpret_cast<ushortT(*)[264]>(smem);   // aliases Hh
  int* sCombo = reinterpret_cast<int*>(smem + 33792);

  const int tid = threadIdx.x;
  const int wv = tid >> 6, lane = tid & 63, quad = lane >> 4, c0 = lane & 15;

  const int blk = blockIdx.x;
  const int b = blk / 63;
  const int p0 = (blk % 63) * 32;

  // ---- phase 1: presence combos (one thread per token) ----
  if (tid < 32) {
    int p = p0 + tid;
    int pa = presence[b * 64 + idx_i[p]];
    int pb = presence[b * 64 + idx_j[p]];
    sCombo[tid] = pa ? (pb ? 0 : 1) : (pb ? 2 : 3);
  }

  // ---- phase 2 round A (ops 0-3 -> H cols 0..255), barrier-free ----
#pragma unroll
  for (int tile = 0; tile < 2; ++tile) {
    int p = p0 + tile * 16 + c0;
    const float* Ax = x + (size_t)(b * 64 + idx_i[p]) * 128 + quad * 8;
    const float* Bx = x + (size_t)(b * 64 + idx_j[p]) * 128 + quad * 8;
    float af[32], bf[32];
    ldrow(Ax, af);
    ldrow(Bx, bf);
    float sa = 0.f, sb = 0.f;
#pragma unroll
    for (int q = 0; q < 32; ++q) { sa = fmaf(af[q], af[q], sa); sb = fmaf(bf[q], bf[q], sb); }
    sa += __shfl_xor(sa, 16); sb += __shfl_xor(sb, 16);
    sa += __shfl_xor(sa, 32); sb += __shfl_xor(sb, 32);
    float invA = 1.f / (sqrtf(sa) + EPS);
    float invB = 1.f / (sqrtf(sb) + EPS);
    p2op<0, 0, false>(tile, wv, lane, quad, c0, af, bf, invA, invB, Hh, Hl, W1p, ops_b1);
    p2op<1, 1, false>(tile, wv, lane, quad, c0, af, bf, invA, invB, Hh, Hl, W1p, ops_b1);
    p2op<2, 2, false>(tile, wv, lane, quad, c0, af, bf, invA, invB, Hh, Hl, W1p, ops_b1);
    p2op<3, 3, false>(tile, wv, lane, quad, c0, af, bf, invA, invB, Hh, Hl, W1p, ops_b1);
  }
  __syncthreads();   // H round A complete (also covers sCombo)

  // ---- phase 3 init + round A ----
  ffrag u[4], v[4];
  {
    int comb0[4], comb1[4];
#pragma unroll
    for (int i = 0; i < 4; ++i) {
      comb0[i] = sCombo[quad * 4 + i];
      comb1[i] = sCombo[16 + quad * 4 + i];
    }
#pragma unroll
    for (int nt4 = 0; nt4 < 4; ++nt4) {
      int col = (wv * 4 + nt4) * 16 + c0;
#pragma unroll
      for (int i = 0; i < 4; ++i) {
        u[nt4][i] = cbias[comb0[i] * 256 + col];
        v[nt4][i] = cbias[comb1[i] * 256 + col];
      }
    }
  }
  p3round(0, wv, lane, quad, c0, Hh, Hl, Gp, u, v);
  __syncthreads();   // H round A consumed

  // ---- phase 2 round B (ops 4(+5 derived), 6, 7 -> H cols 0..255) ----
#pragma unroll
  for (int tile = 0; tile < 2; ++tile) {
    int p = p0 + tile * 16 + c0;
    const float* Ax = x + (size_t)(b * 64 + idx_i[p]) * 128 + quad * 8;
    const float* Bx = x + (size_t)(b * 64 + idx_j[p]) * 128 + quad * 8;
    float af[32], bf[32];
    ldrow(Ax, af);
    ldrow(Bx, bf);
    p2op<4, 0, true >(tile, wv, lane, quad, c0, af, bf, 0.f, 0.f, Hh, Hl, W1p, ops_b1);
    p2op<6, 2, false>(tile, wv, lane, quad, c0, af, bf, 0.f, 0.f, Hh, Hl, W1p, ops_b1);
    p2op<7, 3, false>(tile, wv, lane, quad, c0, af, bf, 0.f, 0.f, Hh, Hl, W1p, ops_b1);
  }
  __syncthreads();   // H round B complete

  p3round(1, wv, lane, quad, c0, Hh, Hl, Gp, u, v);
  __syncthreads();   // H fully consumed -> D may alias

  // ---- write Hid (relu, bf16-hi) into D ----
#pragma unroll
  for (int nt4 = 0; nt4 < 4; ++nt4) {
    int col = (wv * 4 + nt4) * 16 + c0;
#pragma unroll
    for (int i = 0; i < 4; ++i) {
      Dh[quad * 4 + i][col] = bf_hi(fmaxf(u[nt4][i], 0.f));
      Dh[16 + quad * 4 + i][col] = bf_hi(fmaxf(v[nt4][i], 0.f));
    }
  }
  __syncthreads();

  // ---- phase 4: out = Hid @ fus_W2 + fus_b2 ----
  ffrag o[2], q[2];
#pragma unroll
  for (int nt2 = 0; nt2 < 2; ++nt2) {
    float bias = fus_b2[(wv * 2 + nt2) * 16 + c0];
    o[nt2] = ffrag{bias, bias, bias, bias};
    q[nt2] = o[nt2];
  }
#pragma unroll
  for (int kk = 0; kk < 8; ++kk) {
    bfrag dh0 = *(const bfrag*)&Dh[c0][kk * 32 + quad * 8];
    bfrag dh1 = *(const bfrag*)&Dh[16 + c0][kk * 32 + quad * 8];
#pragma unroll
    for (int nt2 = 0; nt2 < 2; ++nt2) {
      bfrag w = *(const bfrag*)(W2p + (((wv * 2 + nt2) * 8 + kk) * 64 + lane) * 8);
      o[nt2] = MFMA(dh0, w, o[nt2]);
      q[nt2] = MFMA(dh1, w, q[nt2]);
    }
  }
#pragma unroll
  for (int nt2 = 0; nt2 < 2; ++nt2) {
    int col = (wv * 2 + nt2) * 16 + c0;
#pragma unroll
    for (int i = 0; i < 4; ++i) {
      int row = quad * 4 + i;
      out[(size_t)(b * 2016 + p0 + row) * 128 + col] = o[nt2][i];
      out[(size_t)(b * 2016 + p0 + 16 + row) * 128 + col] = q[nt2][i];
    }
  }
}

// ---------------------------------------------------------------------------
extern "C" void kernel_launch(void* const* d_in, const int* in_sizes, int n_in,
                              void* d_out, int out_size, void* d_ws, size_t ws_size,
                              hipStream_t stream) {
  const float* x        = (const float*)d_in[0];
  const int*   presence = (const int*)d_in[1];
  const int*   idx_i    = (const int*)d_in[2];
  const int*   idx_j    = (const int*)d_in[3];
  const float* ops_W1   = (const float*)d_in[4];
  const float* ops_b1   = (const float*)d_in[5];
  const float* ops_W2   = (const float*)d_in[6];
  const float* ops_b2   = (const float*)d_in[7];
  const float* pres_W1  = (const float*)d_in[8];
  const float* pres_b1  = (const float*)d_in[9];
  const float* pres_W2  = (const float*)d_in[10];
  const float* pres_b2  = (const float*)d_in[11];
  const float* fus_W1   = (const float*)d_in[12];
  const float* fus_b1   = (const float*)d_in[13];
  const float* fus_W2   = (const float*)d_in[14];
  const float* fus_b2   = (const float*)d_in[15];

  char* ws = (char*)d_ws;
  ushortT* Gp  = (ushortT*)(ws);            // 512*256*2   = 262144 B
  ushortT* W1p = (ushortT*)(ws + 262144);   // 8*4*4*512*2 = 131072 B
  ushortT* W2p = (ushortT*)(ws + 393216);   // 8*8*512*2   =  65536 B
  float*   CB  = (float*)(ws + 458752);     // 4*256*4     =   4096 B

  prologue<<<564, 256, 0, stream>>>(ops_W1, ops_W2, ops_b2, pres_W1, pres_b1,
                                    pres_W2, pres_b2, fus_W1, fus_b1, fus_W2,
                                    Gp, W1p, W2p, CB);
  // 64 batches * 63 blocks, 32 tokens each = 129024 tokens
  drel_main<<<4032, 256, 0, stream>>>(x, presence, idx_i, idx_j, ops_b1, fus_b2,
                                      W1p, Gp, W2p, CB, (float*)d_out);
}

// Round 5
// 385.331 us; speedup vs baseline: 1.3807x; 1.3807x over previous
//
#include <hip/hip_runtime.h>

#define EPS 1e-6f

using bfrag = __attribute__((ext_vector_type(8))) short;   // 8 bf16
using ffrag = __attribute__((ext_vector_type(4))) float;   // C/D frag
typedef unsigned short ushortT;

#define MFMA(a, b, c) __builtin_amdgcn_mfma_f32_16x16x32_bf16((a), (b), (c), 0, 0, 0)

__device__ __forceinline__ ushortT bf_hi(float x) {
  unsigned u = __builtin_bit_cast(unsigned, x);
  return (ushortT)((u + 0x7FFFu + ((u >> 16) & 1u)) >> 16);
}
__device__ __forceinline__ float bf_f(ushortT h) {
  unsigned u = (unsigned)h << 16;
  return __builtin_bit_cast(float, u);
}
__device__ __forceinline__ void split_bf(float f, short& h, short& l) {
  ushortT hi = bf_hi(f);
  h = (short)hi;
  l = (short)bf_hi(f - bf_f(hi));
}
__device__ __forceinline__ int op_of(int k) { return (k < 4) ? k : ((k >> 1) + 2); }

// ---------------------------------------------------------------------------
// ws layout: Gp 0..256K | W1p 256K..384K | W2p 384K..448K | cbias 448K+
// Weights bf16 (hi-only), packed B-fragment order for W[K x N]:
//   elem j of lane L = W[kk*32 + (L>>4)*8 + j][nt*16 + (L&15)]
// ---------------------------------------------------------------------------
__global__ void prologue(const float* __restrict__ ops_W1,
                         const float* __restrict__ ops_W2,
                         const float* __restrict__ ops_b2,
                         const float* __restrict__ pres_W1,
                         const float* __restrict__ pres_b1,
                         const float* __restrict__ pres_W2,
                         const float* __restrict__ pres_b2,
                         const float* __restrict__ fus_W1,
                         const float* __restrict__ fus_b1,
                         const float* __restrict__ fus_W2,
                         ushortT* __restrict__ Gp,
                         ushortT* __restrict__ W1p,
                         ushortT* __restrict__ W2p,
                         float* __restrict__ cb) {
  const int blk = blockIdx.x;
  const int tid = threadIdx.x;

  if (blk < 512) {
    // ---- pack G: G[r][n] = sum_d ops_W2[op(k)][h][d] * fus_W1[k*128+d][n]
    int r = blk, n = tid;
    int k = r >> 6;
    int op = op_of(k);
    const float* w2 = ops_W2 + (size_t)(op * 64 + (r & 63)) * 128;
    const float* w1 = fus_W1 + (size_t)(k * 128) * 256 + n;
    float a0 = 0.f, a1 = 0.f, a2 = 0.f, a3 = 0.f;
#pragma unroll 8
    for (int d = 0; d < 128; d += 4) {
      a0 = fmaf(w2[d], w1[(size_t)d * 256], a0);
      a1 = fmaf(w2[d + 1], w1[(size_t)(d + 1) * 256], a1);
      a2 = fmaf(w2[d + 2], w1[(size_t)(d + 2) * 256], a2);
      a3 = fmaf(w2[d + 3], w1[(size_t)(d + 3) * 256], a3);
    }
    float acc = (a0 + a1) + (a2 + a3);
    int nt = n >> 4, kk = r >> 5, quad = (r >> 3) & 3, j = r & 7;
    int lane = quad * 16 + (n & 15);
    Gp[((nt * 16 + kk) * 64 + lane) * 8 + j] = bf_hi(acc);
  } else if (blk < 544) {
    // ---- pack ops_W1: [k 8][nt 4][kk 4][lane 64][j 8]
    int gid = (blk - 512) * 256 + tid;
    int lane = gid & 63, kk = (gid >> 6) & 3, nt = (gid >> 8) & 3, k = gid >> 10;
    int op = op_of(k);
    int col = nt * 16 + (lane & 15);
#pragma unroll
    for (int j = 0; j < 8; ++j) {
      int d = kk * 32 + ((lane >> 4) & 3) * 8 + j;
      W1p[gid * 8 + j] = bf_hi(ops_W1[((size_t)op * 128 + d) * 64 + col]);
    }
  } else if (blk < 560) {
    // ---- pack fus_W2: [nt 8][kk 8][lane 64][j 8]
    int gid = (blk - 544) * 256 + tid;
    int lane = gid & 63, kk = (gid >> 6) & 7, nt = gid >> 9;
    int col = nt * 16 + (lane & 15);
#pragma unroll
    for (int j = 0; j < 8; ++j) {
      int d = kk * 32 + ((lane >> 4) & 3) * 8 + j;
      W2p[gid * 8 + j] = bf_hi(fus_W2[(size_t)d * 128 + col]);
    }
  } else {
    // ---- cbias[c][n]
    int c = blk - 560, n = tid;
    __shared__ float hrelu[64];
    __shared__ float ptok[128];
    if (n < 64) hrelu[n] = fmaxf(pres_W1[c * 64 + n] + pres_b1[n], 0.f);
    __syncthreads();
    if (n < 128) {
      float p0 = pres_b2[n], p1 = 0.f;
#pragma unroll 8
      for (int hh = 0; hh < 64; hh += 2) {
        p0 = fmaf(hrelu[hh], pres_W2[hh * 128 + n], p0);
        p1 = fmaf(hrelu[hh + 1], pres_W2[(hh + 1) * 128 + n], p1);
      }
      ptok[n] = p0 + p1;
    }
    __syncthreads();
    float acc = fus_b1[n];
#pragma unroll 4
    for (int d = 0; d < 128; ++d)
      acc = fmaf(ptok[d], fus_W1[(size_t)(1024 + d) * 256 + n], acc);
    float acc2 = 0.f;  // ops_b2 fold (zeros in setup, kept for generality)
    for (int k = 0; k < 8; ++k) {
      int op = op_of(k);
#pragma unroll 4
      for (int d = 0; d < 128; ++d)
        acc2 = fmaf(ops_b2[op * 128 + d], fus_W1[(size_t)(k * 128 + d) * 256 + n], acc2);
    }
    cb[c * 256 + n] = acc + acc2;
  }
}

// ---------------------------------------------------------------------------
// Main: 32 tokens/block (two 16-row M-tiles), 256 threads = 4 waves.
// x[b] (all 64 node rows, 32 KB) staged ONCE in LDS, coalesced; A-fragments
// built in registers from LDS (no global scatter, no F round-trip).
// 4 split-K rounds of 128 H-cols: H LDS halved -> total 50.2 KB, 3 blocks/CU.
// Weights bf16 (hi); activations split hi+lo (2 MFMAs/product).
// k=5 feature = -(k=4), same op-4 MLP -> derived from k=4 accumulator.
// ---------------------------------------------------------------------------
__device__ __forceinline__ void ldX(const float* Xrow, int quad, float (&r)[32]) {
#pragma unroll
  for (int kk = 0; kk < 4; ++kk) {
    float4 t0 = *(const float4*)(Xrow + kk * 32 + quad * 8);
    float4 t1 = *(const float4*)(Xrow + kk * 32 + quad * 8 + 4);
    r[kk * 8 + 0] = t0.x; r[kk * 8 + 1] = t0.y; r[kk * 8 + 2] = t0.z; r[kk * 8 + 3] = t0.w;
    r[kk * 8 + 4] = t1.x; r[kk * 8 + 5] = t1.y; r[kk * 8 + 6] = t1.z; r[kk * 8 + 7] = t1.w;
  }
}

template <int K, int KB, bool NEG5>
__device__ __forceinline__ void p2op(int tile, int wv, int lane, int quad, int c0,
                                     const float (&af)[32], const float (&bf)[32],
                                     float invA, float invB,
                                     ushortT (*Hh)[136], ushortT (*Hl)[136],
                                     const ushortT* __restrict__ W1p,
                                     const float* __restrict__ ops_b1) {
  bfrag ah[4], al[4];
#pragma unroll
  for (int kk = 0; kk < 4; ++kk) {
#pragma unroll
    for (int j = 0; j < 8; ++j) {
      float a = af[kk * 8 + j], b = bf[kk * 8 + j], f;
      if constexpr (K == 0)      f = a * b;
      else if constexpr (K == 1) f = a + b;
      else if constexpr (K == 2) f = (a * invA) * (b * invB);
      else if constexpr (K == 3) f = fabsf(a - b);
      else if constexpr (K == 4) f = a - b;
      else if constexpr (K == 6) f = a * __builtin_amdgcn_rcpf(b + EPS);
      else                       f = b * __builtin_amdgcn_rcpf(a + EPS);
      short h, l;
      split_bf(f, h, l);
      ah[kk][j] = h;
      al[kk][j] = l;
    }
  }
  constexpr int OP = (K < 4) ? K : ((K >> 1) + 2);
  const ushortT* wp = W1p + ((K * 4 + wv) * 4) * 512 + lane * 8;
  ffrag s = {0.f, 0.f, 0.f, 0.f};
#pragma unroll
  for (int kk = 0; kk < 4; ++kk) {
    bfrag bh = *(const bfrag*)(wp + kk * 512);
    s = MFMA(ah[kk], bh, s);
    s = MFMA(al[kk], bh, s);
  }
  const float bb1 = ops_b1[OP * 64 + wv * 16 + c0];
  const int col = KB * 64 + wv * 16 + c0;
  const int rbase = tile * 16 + quad * 4;
#pragma unroll
  for (int i = 0; i < 4; ++i) {
    short h, l;
    split_bf(fmaxf(s[i] + bb1, 0.f), h, l);
    Hh[rbase + i][col] = (ushortT)h;
    Hl[rbase + i][col] = (ushortT)l;
    if constexpr (NEG5) {   // k=5 feature = -f4, same op-4 W1/b1
      split_bf(fmaxf(-s[i] + bb1, 0.f), h, l);
      Hh[rbase + i][col + 64] = (ushortT)h;
      Hl[rbase + i][col + 64] = (ushortT)l;
    }
  }
}

__device__ __forceinline__ void p3round(int r, int wv, int lane, int quad, int c0,
                                        ushortT (*Hh)[136], ushortT (*Hl)[136],
                                        const ushortT* __restrict__ Gp,
                                        ffrag (&u)[4], ffrag (&v)[4]) {
#pragma unroll
  for (int kk = 0; kk < 4; ++kk) {
    bfrag ah0 = *(const bfrag*)&Hh[c0][kk * 32 + quad * 8];
    bfrag al0 = *(const bfrag*)&Hl[c0][kk * 32 + quad * 8];
    bfrag ah1 = *(const bfrag*)&Hh[16 + c0][kk * 32 + quad * 8];
    bfrag al1 = *(const bfrag*)&Hl[16 + c0][kk * 32 + quad * 8];
#pragma unroll
    for (int nt4 = 0; nt4 < 4; ++nt4) {
      bfrag g = *(const bfrag*)(Gp + (((wv * 4 + nt4) * 16 + r * 4 + kk) * 64 + lane) * 8);
      u[nt4] = MFMA(ah0, g, u[nt4]);
      u[nt4] = MFMA(al0, g, u[nt4]);
      v[nt4] = MFMA(ah1, g, v[nt4]);
      v[nt4] = MFMA(al1, g, v[nt4]);
    }
  }
}

__global__ __launch_bounds__(256, 3)
void drel_main(const float* __restrict__ x, const int* __restrict__ presence,
               const int* __restrict__ idx_i, const int* __restrict__ idx_j,
               const float* __restrict__ ops_b1, const float* __restrict__ fus_b2,
               const ushortT* __restrict__ W1p, const ushortT* __restrict__ Gp,
               const ushortT* __restrict__ W2p, const float* __restrict__ cbias,
               float* __restrict__ out) {
  __shared__ __align__(16) char smem[51328];
  float   (*Xs)[132]  = reinterpret_cast<float(*)[132]>(smem);            // 33792 B
  ushortT (*Hh)[136]  = reinterpret_cast<ushortT(*)[136]>(smem + 33792);  //  8704 B
  ushortT (*Hl)[136]  = reinterpret_cast<ushortT(*)[136]>(smem + 42496);  //  8704 B
  ushortT (*Dh)[264]  = reinterpret_cast<ushortT(*)[264]>(smem + 33792);  // aliases H
  int* sCombo = reinterpret_cast<int*>(smem + 51200);

  const int tid = threadIdx.x;
  const int wv = tid >> 6, lane = tid & 63, quad = lane >> 4, c0 = lane & 15;

  const int blk = blockIdx.x;
  const int b = blk / 63;
  const int p0 = (blk % 63) * 32;

  // ---- stage x[b] (64 rows x 128 f32) into LDS, fully coalesced ----
  const float* xb = x + (size_t)b * 64 * 128;
#pragma unroll
  for (int it = 0; it < 8; ++it) {
    int i = tid + it * 256;
    int row = i >> 5, c4 = (i & 31) * 4;
    *(float4*)&Xs[row][c4] = *(const float4*)(xb + row * 128 + c4);
  }
  if (tid < 32) {
    int p = p0 + tid;
    int pa = presence[b * 64 + idx_i[p]];
    int pb = presence[b * 64 + idx_j[p]];
    sCombo[tid] = pa ? (pb ? 0 : 1) : (pb ? 2 : 3);
  }

  // token row ids for this lane's two tiles (lane serves token c0 of each tile)
  const int ri0 = idx_i[p0 + c0],      rj0 = idx_j[p0 + c0];
  const int ri1 = idx_i[p0 + 16 + c0], rj1 = idx_j[p0 + 16 + c0];

  // ---- phase 3 accumulators (persist across all 4 rounds) ----
  ffrag u[4], v[4];
  __syncthreads();   // X + sCombo ready
  {
    int comb0[4], comb1[4];
#pragma unroll
    for (int i = 0; i < 4; ++i) {
      comb0[i] = sCombo[quad * 4 + i];
      comb1[i] = sCombo[16 + quad * 4 + i];
    }
#pragma unroll
    for (int nt4 = 0; nt4 < 4; ++nt4) {
      int col = (wv * 4 + nt4) * 16 + c0;
#pragma unroll
      for (int i = 0; i < 4; ++i) {
        u[nt4][i] = cbias[comb0[i] * 256 + col];
        v[nt4][i] = cbias[comb1[i] * 256 + col];
      }
    }
  }

  float af[32], bf[32];

  // ---- round 0: k0,k1 ----
  ldX(Xs[ri0], quad, af); ldX(Xs[rj0], quad, bf);
  p2op<0, 0, false>(0, wv, lane, quad, c0, af, bf, 0.f, 0.f, Hh, Hl, W1p, ops_b1);
  p2op<1, 1, false>(0, wv, lane, quad, c0, af, bf, 0.f, 0.f, Hh, Hl, W1p, ops_b1);
  ldX(Xs[ri1], quad, af); ldX(Xs[rj1], quad, bf);
  p2op<0, 0, false>(1, wv, lane, quad, c0, af, bf, 0.f, 0.f, Hh, Hl, W1p, ops_b1);
  p2op<1, 1, false>(1, wv, lane, quad, c0, af, bf, 0.f, 0.f, Hh, Hl, W1p, ops_b1);
  __syncthreads();
  p3round(0, wv, lane, quad, c0, Hh, Hl, Gp, u, v);
  __syncthreads();

  // ---- round 1: k2 (normalized), k3 ----
  {
    ldX(Xs[ri0], quad, af); ldX(Xs[rj0], quad, bf);
    float sa = 0.f, sb = 0.f;
#pragma unroll
    for (int q = 0; q < 32; ++q) { sa = fmaf(af[q], af[q], sa); sb = fmaf(bf[q], bf[q], sb); }
    sa += __shfl_xor(sa, 16); sb += __shfl_xor(sb, 16);
    sa += __shfl_xor(sa, 32); sb += __shfl_xor(sb, 32);
    float invA = 1.f / (sqrtf(sa) + EPS), invB = 1.f / (sqrtf(sb) + EPS);
    p2op<2, 0, false>(0, wv, lane, quad, c0, af, bf, invA, invB, Hh, Hl, W1p, ops_b1);
    p2op<3, 1, false>(0, wv, lane, quad, c0, af, bf, invA, invB, Hh, Hl, W1p, ops_b1);
    ldX(Xs[ri1], quad, af); ldX(Xs[rj1], quad, bf);
    sa = 0.f; sb = 0.f;
#pragma unroll
    for (int q = 0; q < 32; ++q) { sa = fmaf(af[q], af[q], sa); sb = fmaf(bf[q], bf[q], sb); }
    sa += __shfl_xor(sa, 16); sb += __shfl_xor(sb, 16);
    sa += __shfl_xor(sa, 32); sb += __shfl_xor(sb, 32);
    invA = 1.f / (sqrtf(sa) + EPS); invB = 1.f / (sqrtf(sb) + EPS);
    p2op<2, 0, false>(1, wv, lane, quad, c0, af, bf, invA, invB, Hh, Hl, W1p, ops_b1);
    p2op<3, 1, false>(1, wv, lane, quad, c0, af, bf, invA, invB, Hh, Hl, W1p, ops_b1);
  }
  __syncthreads();
  p3round(1, wv, lane, quad, c0, Hh, Hl, Gp, u, v);
  __syncthreads();

  // ---- round 2: k4 (+k5 = -k4 derived) ----
  ldX(Xs[ri0], quad, af); ldX(Xs[rj0], quad, bf);
  p2op<4, 0, true>(0, wv, lane, quad, c0, af, bf, 0.f, 0.f, Hh, Hl, W1p, ops_b1);
  ldX(Xs[ri1], quad, af); ldX(Xs[rj1], quad, bf);
  p2op<4, 0, true>(1, wv, lane, quad, c0, af, bf, 0.f, 0.f, Hh, Hl, W1p, ops_b1);
  __syncthreads();
  p3round(2, wv, lane, quad, c0, Hh, Hl, Gp, u, v);
  __syncthreads();

  // ---- round 3: k6, k7 (ratios) ----
  ldX(Xs[ri0], quad, af); ldX(Xs[rj0], quad, bf);
  p2op<6, 0, false>(0, wv, lane, quad, c0, af, bf, 0.f, 0.f, Hh, Hl, W1p, ops_b1);
  p2op<7, 1, false>(0, wv, lane, quad, c0, af, bf, 0.f, 0.f, Hh, Hl, W1p, ops_b1);
  ldX(Xs[ri1], quad, af); ldX(Xs[rj1], quad, bf);
  p2op<6, 0, false>(1, wv, lane, quad, c0, af, bf, 0.f, 0.f, Hh, Hl, W1p, ops_b1);
  p2op<7, 1, false>(1, wv, lane, quad, c0, af, bf, 0.f, 0.f, Hh, Hl, W1p, ops_b1);
  __syncthreads();
  p3round(3, wv, lane, quad, c0, Hh, Hl, Gp, u, v);
  __syncthreads();   // H fully consumed -> D may alias

  // ---- write Hid (relu, bf16-hi) into D ----
#pragma unroll
  for (int nt4 = 0; nt4 < 4; ++nt4) {
    int col = (wv * 4 + nt4) * 16 + c0;
#pragma unroll
    for (int i = 0; i < 4; ++i) {
      Dh[quad * 4 + i][col] = bf_hi(fmaxf(u[nt4][i], 0.f));
      Dh[16 + quad * 4 + i][col] = bf_hi(fmaxf(v[nt4][i], 0.f));
    }
  }
  __syncthreads();

  // ---- phase 4: out = Hid @ fus_W2 + fus_b2 ----
  ffrag o[2], q[2];
#pragma unroll
  for (int nt2 = 0; nt2 < 2; ++nt2) {
    float bias = fus_b2[(wv * 2 + nt2) * 16 + c0];
    o[nt2] = ffrag{bias, bias, bias, bias};
    q[nt2] = o[nt2];
  }
#pragma unroll
  for (int kk = 0; kk < 8; ++kk) {
    bfrag dh0 = *(const bfrag*)&Dh[c0][kk * 32 + quad * 8];
    bfrag dh1 = *(const bfrag*)&Dh[16 + c0][kk * 32 + quad * 8];
#pragma unroll
    for (int nt2 = 0; nt2 < 2; ++nt2) {
      bfrag w = *(const bfrag*)(W2p + (((wv * 2 + nt2) * 8 + kk) * 64 + lane) * 8);
      o[nt2] = MFMA(dh0, w, o[nt2]);
      q[nt2] = MFMA(dh1, w, q[nt2]);
    }
  }
#pragma unroll
  for (int nt2 = 0; nt2 < 2; ++nt2) {
    int col = (wv * 2 + nt2) * 16 + c0;
#pragma unroll
    for (int i = 0; i < 4; ++i) {
      int row = quad * 4 + i;
      out[(size_t)(b * 2016 + p0 + row) * 128 + col] = o[nt2][i];
      out[(size_t)(b * 2016 + p0 + 16 + row) * 128 + col] = q[nt2][i];
    }
  }
}

// ---------------------------------------------------------------------------
extern "C" void kernel_launch(void* const* d_in, const int* in_sizes, int n_in,
                              void* d_out, int out_size, void* d_ws, size_t ws_size,
                              hipStream_t stream) {
  const float* x        = (const float*)d_in[0];
  const int*   presence = (const int*)d_in[1];
  const int*   idx_i    = (const int*)d_in[2];
  const int*   idx_j    = (const int*)d_in[3];
  const float* ops_W1   = (const float*)d_in[4];
  const float* ops_b1   = (const float*)d_in[5];
  const float* ops_W2   = (const float*)d_in[6];
  const float* ops_b2   = (const float*)d_in[7];
  const float* pres_W1  = (const float*)d_in[8];
  const float* pres_b1  = (const float*)d_in[9];
  const float* pres_W2  = (const float*)d_in[10];
  const float* pres_b2  = (const float*)d_in[11];
  const float* fus_W1   = (const float*)d_in[12];
  const float* fus_b1   = (const float*)d_in[13];
  const float* fus_W2   = (const float*)d_in[14];
  const float* fus_b2   = (const float*)d_in[15];

  char* ws = (char*)d_ws;
  ushortT* Gp  = (ushortT*)(ws);            // 512*256*2   = 262144 B
  ushortT* W1p = (ushortT*)(ws + 262144);   // 8*4*4*512*2 = 131072 B
  ushortT* W2p = (ushortT*)(ws + 393216);   // 8*8*512*2   =  65536 B
  float*   CB  = (float*)(ws + 458752);     // 4*256*4     =   4096 B

  prologue<<<564, 256, 0, stream>>>(ops_W1, ops_W2, ops_b2, pres_W1, pres_b1,
                                    pres_W2, pres_b2, fus_W1, fus_b1, fus_W2,
                                    Gp, W1p, W2p, CB);
  // 64 batches * 63 blocks, 32 tokens each = 129024 tokens
  drel_main<<<4032, 256, 0, stream>>>(x, presence, idx_i, idx_j, ops_b1, fus_b2,
                                      W1p, Gp, W2p, CB, (float*)d_out);
}